// Round 1
// baseline (2126.043 us; speedup 1.0000x reference)
//
#include <hip/hip_runtime.h>

// Problem constants (fixed by the reference).
constexpr int Bn = 4;       // batch
constexpr int Tn = 2048;    // seq len
constexpr int Dn = 1024;    // hidden
constexpr int Rn = 64;      // max relative position
constexpr int NREL = 2 * Rn + 1;   // 129
constexpr int QR_STRIDE = 132;     // padded rel-logit row stride (16B-aligned rows)

#define BM 64
#define BN 64
#define BK 16

// ---------------------------------------------------------------------------
// C[M,N] = scale * (A[M,K] @ W[K,N] + bias[N])   (all row-major, fp32)
// M,N multiples of 64; K multiple of 16.
// ---------------------------------------------------------------------------
__global__ __launch_bounds__(256) void gemm_nn_bias(
    const float* __restrict__ A, const float* __restrict__ W,
    const float* __restrict__ bias, float* __restrict__ C,
    int M, int N, int K, float scale)
{
    __shared__ float As[BK][BM + 4];   // transposed A tile, +4 keeps 16B row align
    __shared__ float Bs[BK][BN];       // W tile as-is

    const int tid   = threadIdx.x;
    const int mBase = blockIdx.x * BM;
    const int nBase = blockIdx.y * BN;

    const int a_m = tid >> 2;          // 0..63
    const int a_k = (tid & 3) << 2;    // 0,4,8,12
    const int b_k = tid >> 4;          // 0..15
    const int b_n = (tid & 15) << 2;   // 0..60
    const int ty  = tid >> 4;          // 0..15
    const int tx  = tid & 15;          // 0..15

    const float* Ap = A + (size_t)(mBase + a_m) * K + a_k;
    const float* Wp = W + (size_t)b_k * N + nBase + b_n;

    float acc[4][4] = {};

    for (int k0 = 0; k0 < K; k0 += BK) {
        float4 av = *(const float4*)(Ap + k0);
        float4 bv = *(const float4*)(Wp + (size_t)k0 * N);
        As[a_k + 0][a_m] = av.x;
        As[a_k + 1][a_m] = av.y;
        As[a_k + 2][a_m] = av.z;
        As[a_k + 3][a_m] = av.w;
        *(float4*)&Bs[b_k][b_n] = bv;
        __syncthreads();
#pragma unroll
        for (int k = 0; k < BK; ++k) {
            float4 a = *(const float4*)&As[k][ty << 2];
            float4 b = *(const float4*)&Bs[k][tx << 2];
            float ar[4] = {a.x, a.y, a.z, a.w};
            float br[4] = {b.x, b.y, b.z, b.w};
#pragma unroll
            for (int i = 0; i < 4; ++i)
#pragma unroll
                for (int j = 0; j < 4; ++j)
                    acc[i][j] += ar[i] * br[j];
        }
        __syncthreads();
    }

#pragma unroll
    for (int i = 0; i < 4; ++i) {
        const int row = mBase + (ty << 2) + i;
        const int col = nBase + (tx << 2);
        float4 o;
        o.x = (acc[i][0] + bias[col + 0]) * scale;
        o.y = (acc[i][1] + bias[col + 1]) * scale;
        o.z = (acc[i][2] + bias[col + 2]) * scale;
        o.w = (acc[i][3] + bias[col + 3]) * scale;
        *(float4*)&C[(size_t)row * N + col] = o;
    }
}

// ---------------------------------------------------------------------------
// C[M, QR_STRIDE] (cols < N valid) = A[M,K] @ Bm[N,K]^T    (qr = Q @ rel^T)
// N = 129 (not a multiple of 64): guarded loads/stores on the N dimension.
// ---------------------------------------------------------------------------
__global__ __launch_bounds__(256) void gemm_nt_qr(
    const float* __restrict__ A, const float* __restrict__ Bm,
    float* __restrict__ C, int M, int N, int K)
{
    __shared__ float As[BK][BM + 4];
    __shared__ float Bs[BK][BN + 4];

    const int tid   = threadIdx.x;
    const int mBase = blockIdx.x * BM;
    const int nBase = blockIdx.y * BN;

    const int l_m = tid >> 2;          // 0..63
    const int l_k = (tid & 3) << 2;    // 0,4,8,12
    const int ty  = tid >> 4;
    const int tx  = tid & 15;

    const float* Ap = A + (size_t)(mBase + l_m) * K + l_k;
    const bool bvalid = (nBase + l_m) < N;
    const float* Bp = Bm + (size_t)(nBase + l_m) * K + l_k;

    float acc[4][4] = {};

    for (int k0 = 0; k0 < K; k0 += BK) {
        float4 av = *(const float4*)(Ap + k0);
        float4 bv = bvalid ? *(const float4*)(Bp + k0) : make_float4(0.f, 0.f, 0.f, 0.f);
        As[l_k + 0][l_m] = av.x;
        As[l_k + 1][l_m] = av.y;
        As[l_k + 2][l_m] = av.z;
        As[l_k + 3][l_m] = av.w;
        Bs[l_k + 0][l_m] = bv.x;
        Bs[l_k + 1][l_m] = bv.y;
        Bs[l_k + 2][l_m] = bv.z;
        Bs[l_k + 3][l_m] = bv.w;
        __syncthreads();
#pragma unroll
        for (int k = 0; k < BK; ++k) {
            float4 a = *(const float4*)&As[k][ty << 2];
            float4 b = *(const float4*)&Bs[k][tx << 2];
            float ar[4] = {a.x, a.y, a.z, a.w};
            float br[4] = {b.x, b.y, b.z, b.w};
#pragma unroll
            for (int i = 0; i < 4; ++i)
#pragma unroll
                for (int j = 0; j < 4; ++j)
                    acc[i][j] += ar[i] * br[j];
        }
        __syncthreads();
    }

#pragma unroll
    for (int i = 0; i < 4; ++i) {
        const int row = mBase + (ty << 2) + i;
#pragma unroll
        for (int j = 0; j < 4; ++j) {
            const int col = nBase + (tx << 2) + j;
            if (col < N) C[(size_t)row * QR_STRIDE + col] = acc[i][j];
        }
    }
}

// ---------------------------------------------------------------------------
// Per-batch scores: Out[z,i,j] = mask ? (Q[z]·K[z]^T)[i,j] + qr[z,i,clip(j-i)] : -1e18
// Q pre-scaled by 1/sqrt(D). blockIdx.z = batch.
// ---------------------------------------------------------------------------
__global__ __launch_bounds__(256) void scores_nt(
    const float* __restrict__ Q, const float* __restrict__ Kp,
    const float* __restrict__ QR, const int* __restrict__ mask,
    float* __restrict__ Out)
{
    __shared__ float As[BK][BM + 4];
    __shared__ float Bs[BK][BN + 4];

    const int tid   = threadIdx.x;
    const int mBase = blockIdx.x * BM;
    const int nBase = blockIdx.y * BN;
    const int z     = blockIdx.z;

    const float* A  = Q  + (size_t)z * Tn * Dn;
    const float* Bm = Kp + (size_t)z * Tn * Dn;

    const int l_m = tid >> 2;
    const int l_k = (tid & 3) << 2;
    const int ty  = tid >> 4;
    const int tx  = tid & 15;

    const float* Ap = A  + (size_t)(mBase + l_m) * Dn + l_k;
    const float* Bp = Bm + (size_t)(nBase + l_m) * Dn + l_k;

    float acc[4][4] = {};

    for (int k0 = 0; k0 < Dn; k0 += BK) {
        float4 av = *(const float4*)(Ap + k0);
        float4 bv = *(const float4*)(Bp + k0);
        As[l_k + 0][l_m] = av.x;
        As[l_k + 1][l_m] = av.y;
        As[l_k + 2][l_m] = av.z;
        As[l_k + 3][l_m] = av.w;
        Bs[l_k + 0][l_m] = bv.x;
        Bs[l_k + 1][l_m] = bv.y;
        Bs[l_k + 2][l_m] = bv.z;
        Bs[l_k + 3][l_m] = bv.w;
        __syncthreads();
#pragma unroll
        for (int k = 0; k < BK; ++k) {
            float4 a = *(const float4*)&As[k][ty << 2];
            float4 b = *(const float4*)&Bs[k][tx << 2];
            float ar[4] = {a.x, a.y, a.z, a.w};
            float br[4] = {b.x, b.y, b.z, b.w};
#pragma unroll
            for (int i = 0; i < 4; ++i)
#pragma unroll
                for (int j = 0; j < 4; ++j)
                    acc[i][j] += ar[i] * br[j];
        }
        __syncthreads();
    }

    // Epilogue: relative-position gather + mask.
#pragma unroll
    for (int ii = 0; ii < 4; ++ii) {
        const int i = mBase + (ty << 2) + ii;
        const int j0 = nBase + (tx << 2);
        const float* qrow = QR + ((size_t)z * Tn + i) * QR_STRIDE;
        const size_t rowoff = ((size_t)z * Tn + i) * Tn + j0;
        int4 mv = *(const int4*)(mask + rowoff);
        int mr[4] = {mv.x, mv.y, mv.z, mv.w};
        float o[4];
#pragma unroll
        for (int j = 0; j < 4; ++j) {
            int d = j0 + j - i;
            d = d < -Rn ? -Rn : (d > Rn ? Rn : d);
            o[j] = mr[j] ? (acc[ii][j] + qrow[d + Rn]) : -1e18f;
        }
        float4 ov = {o[0], o[1], o[2], o[3]};
        *(float4*)(Out + rowoff) = ov;
    }
}

extern "C" void kernel_launch(void* const* d_in, const int* in_sizes, int n_in,
                              void* d_out, int out_size, void* d_ws, size_t ws_size,
                              hipStream_t stream) {
    const float* repre = (const float*)d_in[0];
    const int*   mask  = (const int*)  d_in[1];
    const float* st_Wq = (const float*)d_in[2];
    const float* st_bq = (const float*)d_in[3];
    const float* st_Wk = (const float*)d_in[4];
    const float* st_bk = (const float*)d_in[5];
    const float* st_rel= (const float*)d_in[6];
    const float* ed_Wq = (const float*)d_in[7];
    const float* ed_bq = (const float*)d_in[8];
    const float* ed_Wk = (const float*)d_in[9];
    const float* ed_bk = (const float*)d_in[10];
    const float* ed_rel= (const float*)d_in[11];
    float* out = (float*)d_out;

    const size_t MT = (size_t)Bn * Tn;          // 8192 rows
    float* Qst  = (float*)d_ws;
    float* Kst  = Qst  + MT * Dn;
    float* Qed  = Kst  + MT * Dn;
    float* Ked  = Qed  + MT * Dn;
    float* QRst = Ked  + MT * Dn;
    float* QRed = QRst + MT * QR_STRIDE;

    const float qscale = 0.03125f;              // 1/sqrt(1024)

    dim3 blk(256);
    dim3 gp((int)MT / BM, Dn / BN);             // 128 x 16
    gemm_nn_bias<<<gp, blk, 0, stream>>>(repre, st_Wq, st_bq, Qst, (int)MT, Dn, Dn, qscale);
    gemm_nn_bias<<<gp, blk, 0, stream>>>(repre, st_Wk, st_bk, Kst, (int)MT, Dn, Dn, 1.0f);
    gemm_nn_bias<<<gp, blk, 0, stream>>>(repre, ed_Wq, ed_bq, Qed, (int)MT, Dn, Dn, qscale);
    gemm_nn_bias<<<gp, blk, 0, stream>>>(repre, ed_Wk, ed_bk, Ked, (int)MT, Dn, Dn, 1.0f);

    dim3 gq((int)MT / BM, (NREL + BN - 1) / BN); // 128 x 3
    gemm_nt_qr<<<gq, blk, 0, stream>>>(Qst, st_rel, QRst, (int)MT, NREL, Dn);
    gemm_nt_qr<<<gq, blk, 0, stream>>>(Qed, ed_rel, QRed, (int)MT, NREL, Dn);

    dim3 gs(Tn / BM, Tn / BN, Bn);               // 32 x 32 x 4
    scores_nt<<<gs, blk, 0, stream>>>(Qst, Kst, QRst, mask, out);
    scores_nt<<<gs, blk, 0, stream>>>(Qed, Ked, QRed, mask, out + (size_t)Bn * Tn * Tn);
}

// Round 2
// 533.138 us; speedup vs baseline: 3.9878x; 3.9878x over previous
//
#include <hip/hip_runtime.h>

// Problem constants (fixed by the reference).
constexpr int Bn = 4;       // batch
constexpr int Tn = 2048;    // seq len
constexpr int Dn = 1024;    // hidden
constexpr int Rn = 64;      // max relative position
// rel padded to 256 rows (zeros beyond 129) so GEMM staging never goes OOB
constexpr int RELP = 256;
constexpr int QR_STRIDE = 132;

typedef __bf16 bf8 __attribute__((ext_vector_type(8)));
typedef float f32x4 __attribute__((ext_vector_type(4)));

__device__ __forceinline__ unsigned short f2bf(float f) {
    unsigned int u = __float_as_uint(f);
    u += 0x7fffu + ((u >> 16) & 1u);     // round-to-nearest-even
    return (unsigned short)(u >> 16);
}

#define GLDS(g, l)                                                            \
    __builtin_amdgcn_global_load_lds(                                         \
        (const __attribute__((address_space(1))) void*)(g),                   \
        (__attribute__((address_space(3))) void*)(l), 16, 0, 0)

// ---------------------------------------------------------------------------
// 128x128 tile NT bf16 MFMA mainloop (m97 recipe): A[128][K], B[128][K] bf16,
// acc[mi][ni] = 16x16 C-tiles, wave grid 2x2 (each wave owns 64x64).
// ---------------------------------------------------------------------------
__device__ __forceinline__ void mfma_gemm_128(
    const unsigned short* __restrict__ Ab,   // tile row 0 of A (bf16 raw)
    const unsigned short* __restrict__ Bb,   // tile row 0 of B (bf16 raw)
    int K, f32x4 acc[4][4],
    unsigned short* As, unsigned short* Bs)  // [128*32] each
{
    const int tid = threadIdx.x;
    const int r0  = tid >> 2;            // 0..63  staging row
    const int c8  = (tid & 3) * 8;       // staging col (elements)
    const int lane = tid & 63;
    const int w    = tid >> 6;
    const int wm = (w & 1) * 64, wn = (w >> 1) * 64;
    const int l15 = lane & 15, lq = lane >> 4;

    for (int k0 = 0; k0 < K; k0 += 32) {
        __syncthreads();
        GLDS(Ab + (size_t)r0 * K + k0 + c8,        As + r0 * 32 + c8);
        GLDS(Ab + ((size_t)r0 + 64) * K + k0 + c8, As + (r0 + 64) * 32 + c8);
        GLDS(Bb + (size_t)r0 * K + k0 + c8,        Bs + r0 * 32 + c8);
        GLDS(Bb + ((size_t)r0 + 64) * K + k0 + c8, Bs + (r0 + 64) * 32 + c8);
        __syncthreads();
        bf8 a[4], b[4];
#pragma unroll
        for (int i = 0; i < 4; ++i) {
            a[i] = *(const bf8*)&As[(wm + i * 16 + l15) * 32 + lq * 8];
            b[i] = *(const bf8*)&Bs[(wn + i * 16 + l15) * 32 + lq * 8];
        }
#pragma unroll
        for (int i = 0; i < 4; ++i)
#pragma unroll
            for (int j = 0; j < 4; ++j)
                acc[i][j] = __builtin_amdgcn_mfma_f32_16x16x32_bf16(
                    a[i], b[j], acc[i][j], 0, 0, 0);
    }
}

// ---------------------------------------------------------------------------
// Prep kernels
// ---------------------------------------------------------------------------
__global__ __launch_bounds__(256) void cvt_bf16(
    const float* __restrict__ in, unsigned short* __restrict__ out, int n4)
{
    int i = blockIdx.x * 256 + threadIdx.x;
    if (i < n4) {
        float4 v = ((const float4*)in)[i];
        ushort4 o;
        o.x = f2bf(v.x); o.y = f2bf(v.y); o.z = f2bf(v.z); o.w = f2bf(v.w);
        ((ushort4*)out)[i] = o;
    }
}

// W[k][n] fp32 -> WT[n][k] bf16, z selects one of the 4 weights.
__global__ __launch_bounds__(256) void wt_transpose(
    const float* __restrict__ w0, const float* __restrict__ w1,
    const float* __restrict__ w2, const float* __restrict__ w3,
    unsigned short* __restrict__ WT)
{
    __shared__ float t[32][33];
    const int z = blockIdx.z;
    const float* W = z == 0 ? w0 : z == 1 ? w1 : z == 2 ? w2 : w3;
    const int x = blockIdx.x * 32 + threadIdx.x;   // n
    const int y0 = blockIdx.y * 32;                // k
#pragma unroll
    for (int j = 0; j < 32; j += 8)
        t[threadIdx.y + j][threadIdx.x] = W[(size_t)(y0 + threadIdx.y + j) * Dn + x];
    __syncthreads();
    unsigned short* o = WT + (size_t)z * Dn * Dn;
    const int n0 = blockIdx.x * 32;
#pragma unroll
    for (int j = 0; j < 32; j += 8)
        o[(size_t)(n0 + threadIdx.y + j) * Dn + y0 + threadIdx.x] =
            f2bf(t[threadIdx.x][threadIdx.y + j]);
}

// rel [129][1024] fp32 -> relb [256][1024] bf16, rows >=129 zero. blockIdx.y=side.
__global__ __launch_bounds__(256) void rel_pad(
    const float* __restrict__ st_rel, const float* __restrict__ ed_rel,
    unsigned short* __restrict__ relb)
{
    const int z = blockIdx.y;
    const float* in = z ? ed_rel : st_rel;
    const int i4 = blockIdx.x * 256 + threadIdx.x;   // over 256*1024/4
    const int row = (i4 * 4) >> 10;
    const int col = (i4 * 4) & 1023;
    ushort4 o; o.x = 0; o.y = 0; o.z = 0; o.w = 0;
    if (row < 2 * Rn + 1) {
        float4 v = *(const float4*)(in + (size_t)row * 1024 + col);
        o.x = f2bf(v.x); o.y = f2bf(v.y); o.z = f2bf(v.z); o.w = f2bf(v.w);
    }
    ((ushort4*)(relb + (size_t)z * RELP * 1024))[i4] = o;
}

// ---------------------------------------------------------------------------
// Projections: out[z] = bf16( (X @ W[z]^T + b[z]) * scale[z] ), z in 0..3
//   z: 0=st_q (scaled), 1=st_k, 2=ed_q (scaled), 3=ed_k
// ---------------------------------------------------------------------------
__global__ __launch_bounds__(256) void proj_gemm(
    const unsigned short* __restrict__ Xb, const unsigned short* __restrict__ Wb,
    const float* __restrict__ b0, const float* __restrict__ b1,
    const float* __restrict__ b2, const float* __restrict__ b3,
    unsigned short* __restrict__ outQK, float qscale)
{
    __shared__ unsigned short As[128 * 32], Bs[128 * 32];
    const int z = blockIdx.z;
    const float* bias = z == 0 ? b0 : z == 1 ? b1 : z == 2 ? b2 : b3;
    const float scale = (z & 1) ? 1.0f : qscale;

    const unsigned short* Ab = Xb + (size_t)blockIdx.x * 128 * Dn;
    const unsigned short* Bb = Wb + ((size_t)z * Dn + blockIdx.y * 128) * Dn;

    f32x4 zero = {0.f, 0.f, 0.f, 0.f};
    f32x4 acc[4][4];
#pragma unroll
    for (int i = 0; i < 4; ++i)
#pragma unroll
        for (int j = 0; j < 4; ++j) acc[i][j] = zero;

    mfma_gemm_128(Ab, Bb, Dn, acc, As, Bs);

    const int tid = threadIdx.x, lane = tid & 63, w = tid >> 6;
    const int wm = (w & 1) * 64, wn = (w >> 1) * 64;
    const int l15 = lane & 15, lq = lane >> 4;
    unsigned short* out = outQK + (size_t)z * (size_t)Bn * Tn * Dn;

#pragma unroll
    for (int ni = 0; ni < 4; ++ni) {
        const int col = blockIdx.y * 128 + wn + ni * 16 + l15;
        const float bv = bias[col];
#pragma unroll
        for (int mi = 0; mi < 4; ++mi) {
#pragma unroll
            for (int r = 0; r < 4; ++r) {
                const int row = blockIdx.x * 128 + wm + mi * 16 + lq * 4 + r;
                out[(size_t)row * Dn + col] = f2bf((acc[mi][ni][r] + bv) * scale);
            }
        }
    }
}

// ---------------------------------------------------------------------------
// qr[z] = Q[z] @ rel[z]^T  (fp32 out, cols < 129 valid, stride 132). z=side.
// ---------------------------------------------------------------------------
__global__ __launch_bounds__(256) void qr_gemm(
    const unsigned short* __restrict__ QKb, const unsigned short* __restrict__ relb,
    float* __restrict__ QR)
{
    __shared__ unsigned short As[128 * 32], Bs[128 * 32];
    const int z = blockIdx.z;
    const unsigned short* Ab = QKb + ((size_t)(z * 2) * Bn * Tn + blockIdx.x * 128) * Dn;
    const unsigned short* Bb = relb + ((size_t)z * RELP + blockIdx.y * 128) * Dn;

    f32x4 zero = {0.f, 0.f, 0.f, 0.f};
    f32x4 acc[4][4];
#pragma unroll
    for (int i = 0; i < 4; ++i)
#pragma unroll
        for (int j = 0; j < 4; ++j) acc[i][j] = zero;

    mfma_gemm_128(Ab, Bb, Dn, acc, As, Bs);

    const int tid = threadIdx.x, lane = tid & 63, w = tid >> 6;
    const int wm = (w & 1) * 64, wn = (w >> 1) * 64;
    const int l15 = lane & 15, lq = lane >> 4;
    float* out = QR + (size_t)z * (size_t)Bn * Tn * QR_STRIDE;

#pragma unroll
    for (int ni = 0; ni < 4; ++ni) {
        const int col = blockIdx.y * 128 + wn + ni * 16 + l15;
        if (col >= 2 * Rn + 1) continue;
#pragma unroll
        for (int mi = 0; mi < 4; ++mi) {
#pragma unroll
            for (int r = 0; r < 4; ++r) {
                const int row = blockIdx.x * 128 + wm + mi * 16 + lq * 4 + r;
                out[(size_t)row * QR_STRIDE + col] = acc[mi][ni][r];
            }
        }
    }
}

// ---------------------------------------------------------------------------
// scores: Out[side,bt,i,j] = mask ? Q·K^T + qr[i, clip(j-i)] : -1e18
// z = side*4 + batch.
// ---------------------------------------------------------------------------
__global__ __launch_bounds__(256) void scores_gemm(
    const unsigned short* __restrict__ QKb, const float* __restrict__ QR,
    const int* __restrict__ mask, float* __restrict__ Out)
{
    __shared__ unsigned short As[128 * 32], Bs[128 * 32];
    const int z = blockIdx.z;
    const int side = z >> 2, bt = z & 3;

    const unsigned short* Ab =
        QKb + ((size_t)side * 2 * Bn * Tn + (size_t)bt * Tn + blockIdx.x * 128) * Dn;
    const unsigned short* Bb =
        QKb + (((size_t)side * 2 + 1) * Bn * Tn + (size_t)bt * Tn + blockIdx.y * 128) * Dn;
    const float* QRb = QR + ((size_t)side * Bn * Tn + (size_t)bt * Tn) * QR_STRIDE;
    const int* maskb = mask + (size_t)bt * Tn * Tn;
    float* outb = Out + ((size_t)side * Bn + bt) * (size_t)Tn * Tn;

    f32x4 zero = {0.f, 0.f, 0.f, 0.f};
    f32x4 acc[4][4];
#pragma unroll
    for (int i = 0; i < 4; ++i)
#pragma unroll
        for (int j = 0; j < 4; ++j) acc[i][j] = zero;

    mfma_gemm_128(Ab, Bb, Dn, acc, As, Bs);

    const int tid = threadIdx.x, lane = tid & 63, w = tid >> 6;
    const int wm = (w & 1) * 64, wn = (w >> 1) * 64;
    const int l15 = lane & 15, lq = lane >> 4;

#pragma unroll
    for (int mi = 0; mi < 4; ++mi) {
#pragma unroll
        for (int r = 0; r < 4; ++r) {
            const int i = blockIdx.x * 128 + wm + mi * 16 + lq * 4 + r;
            const float* qrow = QRb + (size_t)i * QR_STRIDE;
            const int* mrow = maskb + (size_t)i * Tn;
            float* orow = outb + (size_t)i * Tn;
#pragma unroll
            for (int ni = 0; ni < 4; ++ni) {
                const int j = blockIdx.y * 128 + wn + ni * 16 + l15;
                int d = j - i;
                d = d < -Rn ? -Rn : (d > Rn ? Rn : d);
                const float qv = qrow[d + Rn];
                orow[j] = mrow[j] ? acc[mi][ni][r] + qv : -1e18f;
            }
        }
    }
}

extern "C" void kernel_launch(void* const* d_in, const int* in_sizes, int n_in,
                              void* d_out, int out_size, void* d_ws, size_t ws_size,
                              hipStream_t stream) {
    const float* repre  = (const float*)d_in[0];
    const int*   mask   = (const int*)  d_in[1];
    const float* st_Wq  = (const float*)d_in[2];
    const float* st_bq  = (const float*)d_in[3];
    const float* st_Wk  = (const float*)d_in[4];
    const float* st_bk  = (const float*)d_in[5];
    const float* st_rel = (const float*)d_in[6];
    const float* ed_Wq  = (const float*)d_in[7];
    const float* ed_bq  = (const float*)d_in[8];
    const float* ed_Wk  = (const float*)d_in[9];
    const float* ed_bk  = (const float*)d_in[10];
    const float* ed_rel = (const float*)d_in[11];
    float* out = (float*)d_out;

    const size_t MT = (size_t)Bn * Tn;   // 8192

    unsigned short* Xb   = (unsigned short*)d_ws;          // [8192][1024]
    unsigned short* Wb   = Xb + MT * Dn;                   // [4][1024][1024]
    unsigned short* relb = Wb + (size_t)4 * Dn * Dn;       // [2][256][1024]
    unsigned short* QKb  = relb + (size_t)2 * RELP * Dn;   // [4][8192][1024]
    float* QRbuf = (float*)(QKb + (size_t)4 * MT * Dn);    // [2][8192][132]

    const float qscale = 0.03125f;       // 1/sqrt(1024)
    dim3 blk(256);

    // Prep
    {
        int n4 = (int)(MT * Dn / 4);
        cvt_bf16<<<dim3((n4 + 255) / 256), blk, 0, stream>>>(repre, Xb, n4);
        wt_transpose<<<dim3(32, 32, 4), dim3(32, 8), 0, stream>>>(
            st_Wq, st_Wk, ed_Wq, ed_Wk, Wb);
        rel_pad<<<dim3(RELP * Dn / 4 / 256, 2), blk, 0, stream>>>(st_rel, ed_rel, relb);
    }

    // Projections (z: 0=st_q,1=st_k,2=ed_q,3=ed_k)
    proj_gemm<<<dim3((int)MT / 128, Dn / 128, 4), blk, 0, stream>>>(
        Xb, Wb, st_bq, st_bk, ed_bq, ed_bk, QKb, qscale);

    // qr (z=side)
    qr_gemm<<<dim3((int)MT / 128, RELP / 128, 2), blk, 0, stream>>>(QKb, relb, QRbuf);

    // scores (z = side*4 + batch)
    scores_gemm<<<dim3(Tn / 128, Tn / 128, 8), blk, 0, stream>>>(QKb, QRbuf, mask, out);
}